// Round 4
// baseline (384.460 us; speedup 1.0000x reference)
//
#include <hip/hip_runtime.h>
#include <hip/hip_fp16.h>

// LightGCN on MI355X. Gather formulation, dinv folded into data:
//   y[n] = dinv[n] * x[n]  (stored fp16, 128B rows)
//   h[d] = dinv[d] * sum_{e in N(d)} y[src_e]
//   next y[d] = dinv[d] * h[d];  out accumulates h in fp32.
// CSR payload is just the src index (4B/edge).
//
// d_in[0]: edge_index int32 [2][1M]  (src = first 1M, dst = next 1M)
// d_in[1]: emb_weight fp32 [150000][64]
// d_out  : full 150000x64 fp32 = (emb + h1 + h2 + h3)/4

constexpr int kNodes     = 150000;
constexpr int kDim       = 64;
constexpr int kEdges     = 1000000;
constexpr int kEmbFloats = kNodes * kDim;          // 9,600,000
constexpr int kScanBlk   = (kNodes + 255) / 256;   // 586

// ---------------- prologue: degree histogram ----------------

__global__ __launch_bounds__(256) void hist_kernel(const int* __restrict__ dst,
                                                   int* __restrict__ counts) {
    int e = blockIdx.x * 256 + threadIdx.x;
    if (e < kEdges) atomicAdd(&counts[dst[e]], 1);
}

// ---------------- exclusive scan over counts ----------------

__global__ __launch_bounds__(256) void scan_block_kernel(const int* __restrict__ counts,
                                                         int* __restrict__ off,
                                                         int* __restrict__ sums) {
    __shared__ int lds[256];
    int n = blockIdx.x * 256 + threadIdx.x;
    int c = (n < kNodes) ? counts[n] : 0;
    lds[threadIdx.x] = c;
    __syncthreads();
    int v = c;
    for (int s = 1; s < 256; s <<= 1) {
        int t = (threadIdx.x >= s) ? lds[threadIdx.x - s] : 0;
        __syncthreads();
        v += t;
        lds[threadIdx.x] = v;
        __syncthreads();
    }
    if (n < kNodes) off[n] = v - c;                 // exclusive within block
    if (threadIdx.x == 255) sums[blockIdx.x] = v;   // block total
}

__global__ __launch_bounds__(1024) void scan_sums_kernel(int* __restrict__ sums) {
    __shared__ int lds[1024];
    int v = (threadIdx.x < kScanBlk) ? sums[threadIdx.x] : 0;
    lds[threadIdx.x] = v;
    __syncthreads();
    int acc = v;
    for (int s = 1; s < 1024; s <<= 1) {
        int t = (threadIdx.x >= s) ? lds[threadIdx.x - s] : 0;
        __syncthreads();
        acc += t;
        lds[threadIdx.x] = acc;
        __syncthreads();
    }
    if (threadIdx.x < kScanBlk) sums[threadIdx.x] = acc - v;  // exclusive
}

// fixup + dinv fused (both per-node)
__global__ __launch_bounds__(256) void scan_fixup_kernel(int* __restrict__ off,
                                                         int* __restrict__ cur,
                                                         const int* __restrict__ sums,
                                                         const int* __restrict__ counts,
                                                         float* __restrict__ dinv) {
    int n = blockIdx.x * 256 + threadIdx.x;
    if (n < kNodes) {
        int o = off[n] + sums[blockIdx.x];
        off[n] = o;
        cur[n] = o;
        int c = counts[n];
        dinv[n] = (c > 0) ? rsqrtf((float)c) : 0.0f;
    }
}

// ---------------- fill CSR payload: src index bucketed by dst ----------------

__global__ __launch_bounds__(256) void fill_kernel(const int* __restrict__ src,
                                                   const int* __restrict__ dst,
                                                   int* __restrict__ cur,
                                                   int* __restrict__ pairs) {
    int e = blockIdx.x * 256 + threadIdx.x;
    if (e < kEdges) {
        int s = src[e];
        int d = dst[e];
        int p = atomicAdd(&cur[d], 1);
        pairs[p] = s;
    }
}

// ---------------- prescale: y0 = fp16(emb * dinv) ----------------
// one thread per float4 (4 dims); row = 16 float4.

__global__ __launch_bounds__(256) void prescale_kernel(const float4* __restrict__ emb4,
                                                       const float* __restrict__ dinv,
                                                       int2* __restrict__ y2) {
    int i = blockIdx.x * 256 + threadIdx.x;
    if (i >= kEmbFloats / 4) return;
    int node = i >> 4;
    float dv = dinv[node];
    float4 v = emb4[i];
    __half2 p01 = __floats2half2_rn(v.x * dv, v.y * dv);
    __half2 p23 = __floats2half2_rn(v.z * dv, v.w * dv);
    y2[i] = make_int2(*reinterpret_cast<int*>(&p01), *reinterpret_cast<int*>(&p23));
}

// ---------------- gather layer: one wave per node ----------------
// lane = g*16 + q : g = edge slot (0..3), q = 4-dim chunk within the row.
// Each lane loads 8B (4 halves) of a source row; rows are 128B fp16.
// s = sum over edges of y[src]; h = dinv*s; accOut = (accIn+h)*scale;
// yOut row = fp16(h*dinv) for the next layer.

__global__ __launch_bounds__(256) void gather_kernel(const int* __restrict__ off,
                                                     const int* __restrict__ counts,
                                                     const int* __restrict__ pairs,
                                                     const __half* __restrict__ x16,
                                                     const float4* __restrict__ accIn4,
                                                     float4* __restrict__ accOut4,
                                                     __half* __restrict__ yOut,
                                                     const float* __restrict__ dinv,
                                                     float scale,
                                                     int writeY) {
    int t    = blockIdx.x * 256 + threadIdx.x;
    int node = t >> 6;          // grid covers exactly kNodes*64 threads
    int lane = t & 63;
    int q    = lane & 15;
    int g    = lane >> 4;

    int b   = off[node];
    int cnt = counts[node];

    float4 s = make_float4(0.f, 0.f, 0.f, 0.f);
    for (int base = 0; base < cnt; base += 64) {
        int m = cnt - base;
        if (m > 64) m = 64;
        int mysrc = (lane < m) ? pairs[b + base + lane] : 0;
        for (int i = 0; i < m; i += 4) {
            int slot = i + g;                 // per-lane source slot
            int si   = __shfl(mysrc, slot);   // ds_bpermute
            if (slot < m) {
                const int2* row = (const int2*)(x16 + (size_t)si * kDim);
                int2 r = row[q];
                __half2 h01 = *reinterpret_cast<__half2*>(&r.x);
                __half2 h23 = *reinterpret_cast<__half2*>(&r.y);
                float2 f01 = __half22float2(h01);
                float2 f23 = __half22float2(h23);
                s.x += f01.x; s.y += f01.y;
                s.z += f23.x; s.w += f23.y;
            }
        }
    }

    // reduce across the 4 edge slots (lanes q, q+16, q+32, q+48)
    s.x += __shfl_xor(s.x, 16); s.y += __shfl_xor(s.y, 16);
    s.z += __shfl_xor(s.z, 16); s.w += __shfl_xor(s.w, 16);
    s.x += __shfl_xor(s.x, 32); s.y += __shfl_xor(s.y, 32);
    s.z += __shfl_xor(s.z, 32); s.w += __shfl_xor(s.w, 32);

    if (g == 0) {
        float dv = dinv[node];
        float4 h = make_float4(s.x * dv, s.y * dv, s.z * dv, s.w * dv);
        size_t idx = (size_t)node * (kDim / 4) + q;
        float4 a = accIn4[idx];
        a.x = (a.x + h.x) * scale;
        a.y = (a.y + h.y) * scale;
        a.z = (a.z + h.z) * scale;
        a.w = (a.w + h.w) * scale;
        accOut4[idx] = a;
        if (writeY) {
            __half2 p01 = __floats2half2_rn(h.x * dv, h.y * dv);
            __half2 p23 = __floats2half2_rn(h.z * dv, h.w * dv);
            int2* yrow = (int2*)(yOut + (size_t)node * kDim);
            yrow[q] = make_int2(*reinterpret_cast<int*>(&p01),
                                *reinterpret_cast<int*>(&p23));
        }
    }
}

// ---------------- launch ----------------

extern "C" void kernel_launch(void* const* d_in, const int* in_sizes, int n_in,
                              void* d_out, int out_size, void* d_ws, size_t ws_size,
                              hipStream_t stream) {
    const int*   edge  = (const int*)d_in[0];
    const int*   src   = edge;
    const int*   dst   = edge + kEdges;
    const float* emb_w = (const float*)d_in[1];
    float*       out   = (float*)d_out;

    // Workspace layout (re-poisoned 0xAA each call):
    //   counts : @0          600000
    //   dinv   : @600000     600000
    //   off    : @1200000    600000
    //   cur    : @1800000    600000
    //   sums   : @2400000    2352 (pad)
    //   pairs  : @2402352    4,000,000  (src index per edge, dst-bucketed)
    //   y0     : @6402352    19,200,000 (fp16 rows)
    //   yA     : @25602352   19,200,000
    //   yB     : @44802352   19,200,000   (end ~64.0 MB)
    char*   ws     = (char*)d_ws;
    int*    counts = (int*)(ws);
    float*  dinv   = (float*)(ws + 600000);
    int*    off    = (int*)(ws + 1200000);
    int*    cur    = (int*)(ws + 1800000);
    int*    sums   = (int*)(ws + 2400000);
    int*    pairs  = (int*)(ws + 2402352);
    __half* y0     = (__half*)(ws + 6402352);
    __half* yA     = (__half*)(ws + 25602352);
    __half* yB     = (__half*)(ws + 44802352);

    const int edgeBlocks    = (kEdges + 255) / 256;
    const int nodeBlocks    = kScanBlk;
    const int prescaleBlks  = (kEmbFloats / 4 + 255) / 256;  // 9375
    const int gatherBlocks  = (kNodes * kDim) / 256;         // 37500, exact

    // CSR build + dinv + prescaled fp16 y0
    hipMemsetAsync(counts, 0, (size_t)kNodes * 4, stream);
    hist_kernel<<<edgeBlocks, 256, 0, stream>>>(dst, counts);
    scan_block_kernel<<<nodeBlocks, 256, 0, stream>>>(counts, off, sums);
    scan_sums_kernel<<<1, 1024, 0, stream>>>(sums);
    scan_fixup_kernel<<<nodeBlocks, 256, 0, stream>>>(off, cur, sums, counts, dinv);
    fill_kernel<<<edgeBlocks, 256, 0, stream>>>(src, dst, cur, pairs);
    prescale_kernel<<<prescaleBlks, 256, 0, stream>>>((const float4*)emb_w, dinv,
                                                      (int2*)y0);

    // Layer 1: out = emb + h1 ; yA = dinv*h1
    gather_kernel<<<gatherBlocks, 256, 0, stream>>>(off, counts, pairs, y0,
                                                    (const float4*)emb_w, (float4*)out,
                                                    yA, dinv, 1.0f, 1);
    // Layer 2: out += h2 ; yB = dinv*h2
    gather_kernel<<<gatherBlocks, 256, 0, stream>>>(off, counts, pairs, yA,
                                                    (const float4*)out, (float4*)out,
                                                    yB, dinv, 1.0f, 1);
    // Layer 3: out = (out + h3)/4
    gather_kernel<<<gatherBlocks, 256, 0, stream>>>(off, counts, pairs, yB,
                                                    (const float4*)out, (float4*)out,
                                                    nullptr, dinv, 0.25f, 0);
}

// Round 5
// 291.709 us; speedup vs baseline: 1.3180x; 1.3180x over previous
//
#include <hip/hip_runtime.h>
#include <hip/hip_fp16.h>

// LightGCN on MI355X. Gather formulation, dinv folded into data (y = dinv*h,
// fp16 128B rows). CSR built via LDS-staged two-phase binning:
//   Phase A: bin edges into 586 buckets (256 nodes each) with LDS reorder,
//            payload packed (dst_low8 << 24) | src.
//   Phase B: one block per bucket: LDS hist/scan/place -> coalesced CSR,
//            emits off/counts/dinv.
// Layers 1-2 write only y (19.2MB). Layer 3 reconstructs h1,h2 from y1,y2
// (h = y * sqrt(deg)) and writes out = (emb + h1 + h2 + h3)/4.
//
// d_in[0]: edge_index int32 [2][1M]; d_in[1]: emb_weight fp32 [150000][64]
// d_out  : 150000x64 fp32

constexpr int kNodes     = 150000;
constexpr int kDim       = 64;
constexpr int kEdges     = 1000000;
constexpr int kEmbFloats = kNodes * kDim;            // 9,600,000
constexpr int kBkt       = (kNodes + 255) / 256;     // 586 buckets
constexpr int kBktCap    = 2048;                     // mean 1707, +8.3 sigma
constexpr int kChunk     = 4096;                     // edges per binA block

// ---------------- Phase A: bin edges by dst>>8, LDS-staged ----------------

__global__ __launch_bounds__(1024) void binA_kernel(const int* __restrict__ src,
                                                    const int* __restrict__ dst,
                                                    int* __restrict__ cur,     // [kBkt] cursors (zeroed)
                                                    unsigned* __restrict__ bin) {
    __shared__ int hist[1024];                 // bucket counts -> scan -> cursor
    __shared__ int sexcl[1024];                // exclusive scan snapshot
    __shared__ int gstart[kBkt];               // global reserved start per bucket
    __shared__ unsigned staged[kChunk];        // packed payload, bucket-ordered
    __shared__ unsigned short sbkt[kChunk];    // bucket id per staged slot

    int t      = threadIdx.x;
    int chunk0 = blockIdx.x * kChunk;
    int n      = min(kChunk, kEdges - chunk0);

    hist[t] = 0;
    __syncthreads();

    int myb[4], myd[4];
    for (int j = 0; j < 4; ++j) {
        int i = j * 1024 + t;
        if (i < n) {
            int d = dst[chunk0 + i];
            myb[j] = d >> 8;
            myd[j] = d & 255;
            atomicAdd(&hist[myb[j]], 1);
        } else myb[j] = -1;
    }
    __syncthreads();

    // Hillis-Steele inclusive scan over hist[0..1023]
    int c = hist[t];
    int acc = c;
    for (int s = 1; s < 1024; s <<= 1) {
        int v = (t >= s) ? hist[t - s] : 0;
        __syncthreads();
        acc += v;
        hist[t] = acc;
        __syncthreads();
    }
    int excl = acc - c;
    sexcl[t] = excl;
    if (t < kBkt) gstart[t] = atomicAdd(&cur[t], c);
    hist[t] = excl;                            // reuse as staging cursor
    __syncthreads();

    // place into LDS ordered by bucket
    for (int j = 0; j < 4; ++j) {
        int i = j * 1024 + t;
        if (i < n) {
            int s = src[chunk0 + i];
            unsigned pk = ((unsigned)myd[j] << 24) | (unsigned)s;
            int p = atomicAdd(&hist[myb[j]], 1);
            staged[p] = pk;
            sbkt[p]   = (unsigned short)myb[j];
        }
    }
    __syncthreads();

    // coalesced-run write out: slot i -> bucket region
    for (int j = 0; j < 4; ++j) {
        int i = j * 1024 + t;
        if (i < n) {
            int bu = sbkt[i];
            int gp = gstart[bu] + (i - sexcl[bu]);
            if (gp < kBktCap) bin[(size_t)bu * kBktCap + gp] = staged[i];
        }
    }
}

// ---------------- exclusive scan over bucket sizes ----------------

__global__ __launch_bounds__(1024) void scan_base_kernel(const int* __restrict__ cur,
                                                         int* __restrict__ base) {
    __shared__ int lds[1024];
    int t = threadIdx.x;
    int v = (t < kBkt) ? min(cur[t], kBktCap) : 0;
    lds[t] = v;
    __syncthreads();
    int acc = v;
    for (int s = 1; s < 1024; s <<= 1) {
        int x = (t >= s) ? lds[t - s] : 0;
        __syncthreads();
        acc += x;
        lds[t] = acc;
        __syncthreads();
    }
    if (t < kBkt) base[t] = acc - v;
}

// ---------------- Phase B: per-bucket CSR build + off/counts/dinv ----------------

__global__ __launch_bounds__(256) void binB_kernel(const int* __restrict__ cur,
                                                   const int* __restrict__ base,
                                                   const unsigned* __restrict__ bin,
                                                   int* __restrict__ pairs,
                                                   int* __restrict__ off,
                                                   int* __restrict__ counts,
                                                   float* __restrict__ dinv) {
    __shared__ int lcnt[256];
    __shared__ int stage[kBktCap];

    int b = blockIdx.x;
    int t = threadIdx.x;
    int cnt = min(cur[b], kBktCap);
    int bs  = base[b];
    const unsigned* mybin = bin + (size_t)b * kBktCap;

    lcnt[t] = 0;
    __syncthreads();
    for (int i = t; i < cnt; i += 256) atomicAdd(&lcnt[mybin[i] >> 24], 1);
    __syncthreads();

    int c = lcnt[t];
    int acc = c;
    for (int s = 1; s < 256; s <<= 1) {
        int v = (t >= s) ? lcnt[t - s] : 0;
        __syncthreads();
        acc += v;
        lcnt[t] = acc;
        __syncthreads();
    }
    int excl = acc - c;

    int node = (b << 8) + t;
    if (node < kNodes) {
        off[node]    = bs + excl;
        counts[node] = c;
        dinv[node]   = (c > 0) ? rsqrtf((float)c) : 0.0f;
    }
    lcnt[t] = excl;                            // reuse as cursor
    __syncthreads();

    for (int i = t; i < cnt; i += 256) {
        unsigned v = mybin[i];
        int p = atomicAdd(&lcnt[v >> 24], 1);
        stage[p] = (int)(v & 0x00FFFFFFu);
    }
    __syncthreads();
    for (int i = t; i < cnt; i += 256) pairs[bs + i] = stage[i];
}

// ---------------- prescale: y0 = fp16(emb * dinv) ----------------

__global__ __launch_bounds__(256) void prescale_kernel(const float4* __restrict__ emb4,
                                                       const float* __restrict__ dinv,
                                                       int2* __restrict__ y2) {
    int i = blockIdx.x * 256 + threadIdx.x;
    if (i >= kEmbFloats / 4) return;
    int node = i >> 4;
    float dv = dinv[node];
    float4 v = emb4[i];
    __half2 p01 = __floats2half2_rn(v.x * dv, v.y * dv);
    __half2 p23 = __floats2half2_rn(v.z * dv, v.w * dv);
    y2[i] = make_int2(*reinterpret_cast<int*>(&p01), *reinterpret_cast<int*>(&p23));
}

// ---------------- gather layer ----------------
// lane = g*16 + q. s = sum over edges of x16[src] (fp16 rows).
// mode 0: write yOut = fp16(dinv*dinv*s)           (layers 1,2)
// mode 1: h3 = dinv*s; h1 = y1*sqrt(cnt); h2 = y2*sqrt(cnt);
//         out = (emb + h1 + h2 + h3) * 0.25        (layer 3)

__global__ __launch_bounds__(256) void gather_kernel(const int* __restrict__ off,
                                                     const int* __restrict__ counts,
                                                     const int* __restrict__ pairs,
                                                     const __half* __restrict__ x16,
                                                     const float* __restrict__ dinv,
                                                     __half* __restrict__ yOut,
                                                     const float4* __restrict__ emb4,
                                                     const __half* __restrict__ y1,
                                                     const __half* __restrict__ y2,
                                                     float4* __restrict__ out4,
                                                     int mode) {
    int t    = blockIdx.x * 256 + threadIdx.x;
    int node = t >> 6;
    int lane = t & 63;
    int q    = lane & 15;
    int g    = lane >> 4;

    int b   = off[node];
    int cnt = counts[node];

    float4 s = make_float4(0.f, 0.f, 0.f, 0.f);
    for (int base = 0; base < cnt; base += 64) {
        int m = cnt - base;
        if (m > 64) m = 64;
        int mysrc = (lane < m) ? pairs[b + base + lane] : 0;
        for (int i = 0; i < m; i += 4) {
            int slot = i + g;
            int si   = __shfl(mysrc, slot);
            if (slot < m) {
                const int2* row = (const int2*)(x16 + (size_t)si * kDim);
                int2 r = row[q];
                __half2 h01 = *reinterpret_cast<__half2*>(&r.x);
                __half2 h23 = *reinterpret_cast<__half2*>(&r.y);
                float2 f01 = __half22float2(h01);
                float2 f23 = __half22float2(h23);
                s.x += f01.x; s.y += f01.y;
                s.z += f23.x; s.w += f23.y;
            }
        }
    }

    s.x += __shfl_xor(s.x, 16); s.y += __shfl_xor(s.y, 16);
    s.z += __shfl_xor(s.z, 16); s.w += __shfl_xor(s.w, 16);
    s.x += __shfl_xor(s.x, 32); s.y += __shfl_xor(s.y, 32);
    s.z += __shfl_xor(s.z, 32); s.w += __shfl_xor(s.w, 32);

    if (g == 0) {
        float dv = dinv[node];
        if (mode == 0) {
            float dv2 = dv * dv;
            __half2 p01 = __floats2half2_rn(s.x * dv2, s.y * dv2);
            __half2 p23 = __floats2half2_rn(s.z * dv2, s.w * dv2);
            int2* yrow = (int2*)(yOut + (size_t)node * kDim);
            yrow[q] = make_int2(*reinterpret_cast<int*>(&p01),
                                *reinterpret_cast<int*>(&p23));
        } else {
            float sq = sqrtf((float)cnt);          // = 1/dinv (0 if deg 0)
            size_t idx = (size_t)node * (kDim / 4) + q;
            float4 e = emb4[idx];
            int2 r1 = ((const int2*)(y1 + (size_t)node * kDim))[q];
            int2 r2 = ((const int2*)(y2 + (size_t)node * kDim))[q];
            float2 a01 = __half22float2(*reinterpret_cast<__half2*>(&r1.x));
            float2 a23 = __half22float2(*reinterpret_cast<__half2*>(&r1.y));
            float2 b01 = __half22float2(*reinterpret_cast<__half2*>(&r2.x));
            float2 b23 = __half22float2(*reinterpret_cast<__half2*>(&r2.y));
            float4 o;
            o.x = (e.x + (a01.x + b01.x) * sq + s.x * dv) * 0.25f;
            o.y = (e.y + (a01.y + b01.y) * sq + s.y * dv) * 0.25f;
            o.z = (e.z + (a23.x + b23.x) * sq + s.z * dv) * 0.25f;
            o.w = (e.w + (a23.y + b23.y) * sq + s.w * dv) * 0.25f;
            out4[idx] = o;
        }
    }
}

// ---------------- launch ----------------

extern "C" void kernel_launch(void* const* d_in, const int* in_sizes, int n_in,
                              void* d_out, int out_size, void* d_ws, size_t ws_size,
                              hipStream_t stream) {
    const int*   edge  = (const int*)d_in[0];
    const int*   src   = edge;
    const int*   dst   = edge + kEdges;
    const float* emb_w = (const float*)d_in[1];
    float*       out   = (float*)d_out;

    // Workspace layout (re-poisoned 0xAA each call):
    //   cur600  : @0         4096
    //   binBase : @4096      4096
    //   off     : @8192      600000
    //   counts  : @608192    600000
    //   dinv    : @1208192   600000
    //   pairs   : @1808192   4,000,000
    //   bin     : @5808192   586*2048*4 = 4,800,512
    //   y0      : @10608704  19,200,000
    //   yA      : @29808704  19,200,000
    //   yB      : @49008704  19,200,000   (end ~68.2 MB)
    char*     ws      = (char*)d_ws;
    int*      cur     = (int*)(ws);
    int*      binBase = (int*)(ws + 4096);
    int*      off     = (int*)(ws + 8192);
    int*      counts  = (int*)(ws + 608192);
    float*    dinv    = (float*)(ws + 1208192);
    int*      pairs   = (int*)(ws + 1808192);
    unsigned* bin     = (unsigned*)(ws + 5808192);
    __half*   y0      = (__half*)(ws + 10608704);
    __half*   yA      = (__half*)(ws + 29808704);
    __half*   yB      = (__half*)(ws + 49008704);

    const int binABlocks   = (kEdges + kChunk - 1) / kChunk;   // 245
    const int prescaleBlks = (kEmbFloats / 4 + 255) / 256;     // 9375
    const int gatherBlocks = (kNodes * kDim) / 256;            // 37500, exact

    hipMemsetAsync(cur, 0, (size_t)kBkt * 4, stream);
    binA_kernel<<<binABlocks, 1024, 0, stream>>>(src, dst, cur, bin);
    scan_base_kernel<<<1, 1024, 0, stream>>>(cur, binBase);
    binB_kernel<<<kBkt, 256, 0, stream>>>(cur, binBase, bin, pairs, off, counts, dinv);
    prescale_kernel<<<prescaleBlks, 256, 0, stream>>>((const float4*)emb_w, dinv,
                                                      (int2*)y0);

    // Layer 1: yA = fp16(dinv^2 * sum y0[src])
    gather_kernel<<<gatherBlocks, 256, 0, stream>>>(off, counts, pairs, y0, dinv,
                                                    yA, nullptr, nullptr, nullptr,
                                                    nullptr, 0);
    // Layer 2: yB = fp16(dinv^2 * sum yA[src])
    gather_kernel<<<gatherBlocks, 256, 0, stream>>>(off, counts, pairs, yA, dinv,
                                                    yB, nullptr, nullptr, nullptr,
                                                    nullptr, 0);
    // Layer 3: out = (emb + h1 + h2 + h3)/4
    gather_kernel<<<gatherBlocks, 256, 0, stream>>>(off, counts, pairs, yB, dinv,
                                                    nullptr, (const float4*)emb_w,
                                                    yA, yB, (float4*)out, 1);
}

// Round 6
// 280.588 us; speedup vs baseline: 1.3702x; 1.0396x over previous
//
#include <hip/hip_runtime.h>
#include <hip/hip_fp16.h>

// LightGCN on MI355X. Gather formulation, dinv folded into data (y = dinv*x,
// fp16 128B rows). CSR built via LDS-staged two-phase binning (wave-scan based).
// Gather: one wave per node, 8 edge slots x 8 lanes x int4 (16B) row chunks.
// Layers 1-2 write only y (19.2MB). Layer 3 reconstructs h1,h2 from y1,y2
// (h = y * sqrt(deg)) and writes out = (emb + h1 + h2 + h3)/4.
//
// d_in[0]: edge_index int32 [2][1M]; d_in[1]: emb_weight fp32 [150000][64]
// d_out  : 150000x64 fp32

constexpr int kNodes     = 150000;
constexpr int kDim       = 64;
constexpr int kEdges     = 1000000;
constexpr int kEmbFloats = kNodes * kDim;            // 9,600,000
constexpr int kBkt       = (kNodes + 255) / 256;     // 586 buckets
constexpr int kBktCap    = 2048;                     // mean 1707, +8.3 sigma
constexpr int kChunk     = 4096;                     // edges per binA block

__device__ __forceinline__ int wave_incl_scan(int v, int lane) {
    #pragma unroll
    for (int s = 1; s < 64; s <<= 1) {
        int u = __shfl_up(v, s);
        if (lane >= s) v += u;
    }
    return v;
}

// ---------------- Phase A: bin edges by dst>>8, LDS-staged ----------------

__global__ __launch_bounds__(1024) void binA_kernel(const int* __restrict__ src,
                                                    const int* __restrict__ dst,
                                                    int* __restrict__ cur,     // [kBkt] zeroed
                                                    unsigned* __restrict__ bin) {
    __shared__ int hist[1024];
    __shared__ int cursor[1024];
    __shared__ int sexcl[1024];
    __shared__ int gstart[1024];
    __shared__ int wsum[16];
    __shared__ unsigned staged[kChunk];
    __shared__ unsigned short sbkt[kChunk];

    int t      = threadIdx.x;
    int lane   = t & 63;
    int w      = t >> 6;
    int chunk0 = blockIdx.x * kChunk;
    int n      = min(kChunk, kEdges - chunk0);

    hist[t] = 0;
    __syncthreads();

    int myb[4], myd[4];
    #pragma unroll
    for (int j = 0; j < 4; ++j) {
        int i = j * 1024 + t;
        if (i < n) {
            int d = dst[chunk0 + i];
            myb[j] = d >> 8;
            myd[j] = d & 255;
            atomicAdd(&hist[myb[j]], 1);
        } else myb[j] = -1;
    }
    __syncthreads();

    // exclusive scan of hist[0..1023] via wave scans
    int c   = hist[t];
    int inc = wave_incl_scan(c, lane);
    if (lane == 63) wsum[w] = inc;
    __syncthreads();
    if (w == 0) {
        int v  = (lane < 16) ? wsum[lane] : 0;
        int sc = wave_incl_scan(v, lane);
        if (lane < 16) wsum[lane] = sc - v;   // exclusive wave offsets
    }
    __syncthreads();
    int excl = wsum[w] + inc - c;
    sexcl[t]  = excl;
    cursor[t] = excl;
    if (t < kBkt) gstart[t] = atomicAdd(&cur[t], c);
    __syncthreads();

    // place into LDS ordered by bucket
    #pragma unroll
    for (int j = 0; j < 4; ++j) {
        int i = j * 1024 + t;
        if (i < n) {
            int s = src[chunk0 + i];
            unsigned pk = ((unsigned)myd[j] << 24) | (unsigned)s;
            int p = atomicAdd(&cursor[myb[j]], 1);
            staged[p] = pk;
            sbkt[p]   = (unsigned short)myb[j];
        }
    }
    __syncthreads();

    // coalesced-run write out
    #pragma unroll
    for (int j = 0; j < 4; ++j) {
        int i = j * 1024 + t;
        if (i < n) {
            int bu = sbkt[i];
            int gp = gstart[bu] + (i - sexcl[bu]);
            if (gp < kBktCap) bin[(size_t)bu * kBktCap + gp] = staged[i];
        }
    }
}

// ---------------- exclusive scan over bucket sizes ----------------

__global__ __launch_bounds__(1024) void scan_base_kernel(const int* __restrict__ cur,
                                                         int* __restrict__ base) {
    __shared__ int wsum[16];
    int t = threadIdx.x;
    int lane = t & 63, w = t >> 6;
    int v = (t < kBkt) ? min(cur[t], kBktCap) : 0;
    int inc = wave_incl_scan(v, lane);
    if (lane == 63) wsum[w] = inc;
    __syncthreads();
    if (w == 0) {
        int x  = (lane < 16) ? wsum[lane] : 0;
        int sc = wave_incl_scan(x, lane);
        if (lane < 16) wsum[lane] = sc - x;
    }
    __syncthreads();
    if (t < kBkt) base[t] = wsum[w] + inc - v;
}

// ---------------- Phase B: per-bucket CSR build + offcnt/dinv ----------------

__global__ __launch_bounds__(256) void binB_kernel(const int* __restrict__ cur,
                                                   const int* __restrict__ base,
                                                   const unsigned* __restrict__ bin,
                                                   int* __restrict__ pairs,
                                                   int2* __restrict__ offcnt,
                                                   float* __restrict__ dinv) {
    __shared__ int lcnt[256];
    __shared__ int cursor[256];
    __shared__ int wsum[4];
    __shared__ int stage[kBktCap];

    int b = blockIdx.x;
    int t = threadIdx.x;
    int lane = t & 63, w = t >> 6;
    int cnt = min(cur[b], kBktCap);
    int bs  = base[b];
    const unsigned* mybin = bin + (size_t)b * kBktCap;

    lcnt[t] = 0;
    __syncthreads();
    for (int i = t; i < cnt; i += 256) atomicAdd(&lcnt[mybin[i] >> 24], 1);
    __syncthreads();

    int c   = lcnt[t];
    int inc = wave_incl_scan(c, lane);
    if (lane == 63) wsum[w] = inc;
    __syncthreads();
    if (t == 0) {
        int a = 0;
        #pragma unroll
        for (int k = 0; k < 4; ++k) { int v = wsum[k]; wsum[k] = a; a += v; }
    }
    __syncthreads();
    int excl = wsum[w] + inc - c;

    int node = (b << 8) + t;
    if (node < kNodes) {
        offcnt[node] = make_int2(bs + excl, c);
        dinv[node]   = (c > 0) ? rsqrtf((float)c) : 0.0f;
    }
    cursor[t] = excl;
    __syncthreads();

    for (int i = t; i < cnt; i += 256) {
        unsigned v = mybin[i];
        int p = atomicAdd(&cursor[v >> 24], 1);
        stage[p] = (int)(v & 0x00FFFFFFu);
    }
    __syncthreads();
    for (int i = t; i < cnt; i += 256) pairs[bs + i] = stage[i];
}

// ---------------- prescale: y0 = fp16(emb * dinv), int4 stores ----------------

__global__ __launch_bounds__(256) void prescale_kernel(const float4* __restrict__ emb4,
                                                       const float* __restrict__ dinv,
                                                       int4* __restrict__ y4) {
    int i = blockIdx.x * 256 + threadIdx.x;      // int4 index = 8 dims
    if (i >= kEmbFloats / 8) return;
    int node = i >> 3;                           // 8 int4 per 64-dim row
    float dv = dinv[node];
    float4 v0 = emb4[(size_t)i * 2];
    float4 v1 = emb4[(size_t)i * 2 + 1];
    __half2 p0 = __floats2half2_rn(v0.x * dv, v0.y * dv);
    __half2 p1 = __floats2half2_rn(v0.z * dv, v0.w * dv);
    __half2 p2 = __floats2half2_rn(v1.x * dv, v1.y * dv);
    __half2 p3 = __floats2half2_rn(v1.z * dv, v1.w * dv);
    int4 wv;
    wv.x = *reinterpret_cast<int*>(&p0); wv.y = *reinterpret_cast<int*>(&p1);
    wv.z = *reinterpret_cast<int*>(&p2); wv.w = *reinterpret_cast<int*>(&p3);
    y4[i] = wv;
}

// ---------------- gather layer: one wave per node, 8 slots x int4 ----------------
// lane = g*8 + q : g = edge slot (0..7), q = 16B chunk (8 dims) within row.
// mode 0: yOut = fp16(dinv^2 * s)              (layers 1,2)
// mode 1: out = (emb + (y1+y2)*sqrt(cnt) + dinv*s) * 0.25   (layer 3)

__global__ __launch_bounds__(256) void gather_kernel(const int2* __restrict__ offcnt,
                                                     const int* __restrict__ pairs,
                                                     const __half* __restrict__ x16,
                                                     const float* __restrict__ dinv,
                                                     __half* __restrict__ yOut,
                                                     const float4* __restrict__ emb4,
                                                     const __half* __restrict__ y1,
                                                     const __half* __restrict__ y2,
                                                     float4* __restrict__ out4,
                                                     int mode) {
    int t    = blockIdx.x * 256 + threadIdx.x;
    int node = t >> 6;
    int lane = t & 63;
    int q    = lane & 7;
    int g    = lane >> 3;

    int2 oc = offcnt[node];
    int b = oc.x, cnt = oc.y;

    float s[8] = {0.f, 0.f, 0.f, 0.f, 0.f, 0.f, 0.f, 0.f};
    for (int base = 0; base < cnt; base += 64) {
        int m = cnt - base;
        if (m > 64) m = 64;
        int mysrc = (lane < m) ? pairs[b + base + lane] : 0;
        for (int i = 0; i < m; i += 8) {
            int slot = i + g;
            int si   = __shfl(mysrc, slot);   // ds_bpermute
            if (slot < m) {
                const int4* row = (const int4*)(x16 + (size_t)si * kDim);
                int4 r = row[q];
                float2 f0 = __half22float2(*reinterpret_cast<__half2*>(&r.x));
                float2 f1 = __half22float2(*reinterpret_cast<__half2*>(&r.y));
                float2 f2 = __half22float2(*reinterpret_cast<__half2*>(&r.z));
                float2 f3 = __half22float2(*reinterpret_cast<__half2*>(&r.w));
                s[0] += f0.x; s[1] += f0.y; s[2] += f1.x; s[3] += f1.y;
                s[4] += f2.x; s[5] += f2.y; s[6] += f3.x; s[7] += f3.y;
            }
        }
    }

    // reduce across the 8 edge slots (xor lane bits 3..5)
    #pragma unroll
    for (int k = 0; k < 8; ++k) s[k] += __shfl_xor(s[k], 8);
    #pragma unroll
    for (int k = 0; k < 8; ++k) s[k] += __shfl_xor(s[k], 16);
    #pragma unroll
    for (int k = 0; k < 8; ++k) s[k] += __shfl_xor(s[k], 32);

    if (g == 0) {
        float dv = dinv[node];
        if (mode == 0) {
            float dv2 = dv * dv;
            __half2 p0 = __floats2half2_rn(s[0] * dv2, s[1] * dv2);
            __half2 p1 = __floats2half2_rn(s[2] * dv2, s[3] * dv2);
            __half2 p2 = __floats2half2_rn(s[4] * dv2, s[5] * dv2);
            __half2 p3 = __floats2half2_rn(s[6] * dv2, s[7] * dv2);
            int4 wv;
            wv.x = *reinterpret_cast<int*>(&p0); wv.y = *reinterpret_cast<int*>(&p1);
            wv.z = *reinterpret_cast<int*>(&p2); wv.w = *reinterpret_cast<int*>(&p3);
            ((int4*)(yOut + (size_t)node * kDim))[q] = wv;
        } else {
            float sq = sqrtf((float)cnt);        // = 1/dinv (0 if deg 0)
            size_t i4 = (size_t)node * 16 + (size_t)q * 2;
            int4 r1 = ((const int4*)(y1 + (size_t)node * kDim))[q];
            int4 r2 = ((const int4*)(y2 + (size_t)node * kDim))[q];
            float4 e0 = emb4[i4];
            float4 e1 = emb4[i4 + 1];
            float2 a0 = __half22float2(*reinterpret_cast<__half2*>(&r1.x));
            float2 a1 = __half22float2(*reinterpret_cast<__half2*>(&r1.y));
            float2 a2 = __half22float2(*reinterpret_cast<__half2*>(&r1.z));
            float2 a3 = __half22float2(*reinterpret_cast<__half2*>(&r1.w));
            float2 c0 = __half22float2(*reinterpret_cast<__half2*>(&r2.x));
            float2 c1 = __half22float2(*reinterpret_cast<__half2*>(&r2.y));
            float2 c2 = __half22float2(*reinterpret_cast<__half2*>(&r2.z));
            float2 c3 = __half22float2(*reinterpret_cast<__half2*>(&r2.w));
            float4 o0, o1;
            o0.x = (e0.x + (a0.x + c0.x) * sq + s[0] * dv) * 0.25f;
            o0.y = (e0.y + (a0.y + c0.y) * sq + s[1] * dv) * 0.25f;
            o0.z = (e0.z + (a1.x + c1.x) * sq + s[2] * dv) * 0.25f;
            o0.w = (e0.w + (a1.y + c1.y) * sq + s[3] * dv) * 0.25f;
            o1.x = (e1.x + (a2.x + c2.x) * sq + s[4] * dv) * 0.25f;
            o1.y = (e1.y + (a2.y + c2.y) * sq + s[5] * dv) * 0.25f;
            o1.z = (e1.z + (a3.x + c3.x) * sq + s[6] * dv) * 0.25f;
            o1.w = (e1.w + (a3.y + c3.y) * sq + s[7] * dv) * 0.25f;
            out4[i4]     = o0;
            out4[i4 + 1] = o1;
        }
    }
}

// ---------------- launch ----------------

extern "C" void kernel_launch(void* const* d_in, const int* in_sizes, int n_in,
                              void* d_out, int out_size, void* d_ws, size_t ws_size,
                              hipStream_t stream) {
    const int*   edge  = (const int*)d_in[0];
    const int*   src   = edge;
    const int*   dst   = edge + kEdges;
    const float* emb_w = (const float*)d_in[1];
    float*       out   = (float*)d_out;

    // Workspace layout (re-poisoned 0xAA each call):
    //   cur     : @0          4096
    //   binBase : @4096       4096
    //   offcnt  : @8192       1,200,000 (int2 per node)
    //   dinv    : @1208192    600,000
    //   pairs   : @1808192    4,000,000
    //   bin     : @5808192    586*2048*4 = 4,800,512
    //   y0      : @10608704   19,200,000
    //   yA      : @29808704   19,200,000
    //   yB      : @49008704   19,200,000   (end ~68.2 MB)
    char*     ws      = (char*)d_ws;
    int*      cur     = (int*)(ws);
    int*      binBase = (int*)(ws + 4096);
    int2*     offcnt  = (int2*)(ws + 8192);
    float*    dinv    = (float*)(ws + 1208192);
    int*      pairs   = (int*)(ws + 1808192);
    unsigned* bin     = (unsigned*)(ws + 5808192);
    __half*   y0      = (__half*)(ws + 10608704);
    __half*   yA      = (__half*)(ws + 29808704);
    __half*   yB      = (__half*)(ws + 49008704);

    const int binABlocks   = (kEdges + kChunk - 1) / kChunk;   // 245
    const int prescaleBlks = (kEmbFloats / 8 + 255) / 256;     // 4688
    const int gatherBlocks = (kNodes * kDim) / 256;            // 37500, exact

    hipMemsetAsync(cur, 0, (size_t)kBkt * 4, stream);
    binA_kernel<<<binABlocks, 1024, 0, stream>>>(src, dst, cur, bin);
    scan_base_kernel<<<1, 1024, 0, stream>>>(cur, binBase);
    binB_kernel<<<kBkt, 256, 0, stream>>>(cur, binBase, bin, pairs, offcnt, dinv);
    prescale_kernel<<<prescaleBlks, 256, 0, stream>>>((const float4*)emb_w, dinv,
                                                      (int4*)y0);

    // Layer 1: yA = fp16(dinv^2 * sum y0[src])
    gather_kernel<<<gatherBlocks, 256, 0, stream>>>(offcnt, pairs, y0, dinv,
                                                    yA, nullptr, nullptr, nullptr,
                                                    nullptr, 0);
    // Layer 2: yB = fp16(dinv^2 * sum yA[src])
    gather_kernel<<<gatherBlocks, 256, 0, stream>>>(offcnt, pairs, yA, dinv,
                                                    yB, nullptr, nullptr, nullptr,
                                                    nullptr, 0);
    // Layer 3: out = (emb + h1 + h2 + h3)/4
    gather_kernel<<<gatherBlocks, 256, 0, stream>>>(offcnt, pairs, yB, dinv,
                                                    nullptr, (const float4*)emb_w,
                                                    yA, yB, (float4*)out, 1);
}